// Round 1
// baseline (575.263 us; speedup 1.0000x reference)
//
#include <hip/hip_runtime.h>

#define B_   16
#define C_   64
#define HW_  65536
#define CHW_ (C_ * HW_)   // 4194304 elements per batch

__device__ __forceinline__ float comp4(float4 v, int i) {
    return i == 0 ? v.x : i == 1 ? v.y : i == 2 ? v.z : v.w;
}

// ---------------------------------------------------------------------------
// Kernel 1: partial Gram matrices.  S[b,c,d] = sum_n X[b,c*HW+n] * X[b,n*C+d]
// Block = (chunk, b), 256 threads = 4 waves; each wave owns an n-slice.
// Lane (si,sj) accumulates an 8x8 (c,d) register tile.  Intra-block LDS
// reduction over the 4 waves, then one 64x64 fp32 partial per block -> ws.
// ---------------------------------------------------------------------------
__global__ __launch_bounds__(256) void k1_gram(const float* __restrict__ x,
                                               float* __restrict__ partial,
                                               int nch, int nb) {
    const int ch   = blockIdx.x;
    const int b    = blockIdx.y;
    const int tid  = threadIdx.x;
    const int w    = tid >> 6;
    const int lane = tid & 63;
    const int si   = lane >> 3;   // c-octet
    const int sj   = lane & 7;    // d-octet
    const int sl   = nb >> 2;     // n per wave
    const int n0   = ch * nb + w * sl;

    const float* qbase = x + (size_t)b * CHW_ + (size_t)(8 * si) * HW_; // + r*HW + n
    const float* kbase = x + (size_t)b * CHW_ + 8 * sj;                 // + n*64 (+0/4)

    float4 acc[8][2];
    #pragma unroll
    for (int r = 0; r < 8; r++) {
        acc[r][0] = make_float4(0.f, 0.f, 0.f, 0.f);
        acc[r][1] = make_float4(0.f, 0.f, 0.f, 0.f);
    }

    for (int nq = n0; nq < n0 + sl; nq += 4) {
        float4 q[8];
        #pragma unroll
        for (int r = 0; r < 8; r++)
            q[r] = *(const float4*)(qbase + r * HW_ + nq);

        float4 ka[4], kb[4];
        #pragma unroll
        for (int kk = 0; kk < 4; kk++) {
            const float* kp = kbase + (size_t)(nq + kk) * C_;
            ka[kk] = *(const float4*)kp;
            kb[kk] = *(const float4*)(kp + 4);
        }

        #pragma unroll
        for (int kk = 0; kk < 4; kk++) {
            const float4 a0 = ka[kk], a1 = kb[kk];
            #pragma unroll
            for (int r = 0; r < 8; r++) {
                const float qv = comp4(q[r], kk);
                acc[r][0].x += qv * a0.x;
                acc[r][0].y += qv * a0.y;
                acc[r][0].z += qv * a0.z;
                acc[r][0].w += qv * a0.w;
                acc[r][1].x += qv * a1.x;
                acc[r][1].y += qv * a1.y;
                acc[r][1].z += qv * a1.z;
                acc[r][1].w += qv * a1.w;
            }
        }
    }

    // intra-block reduction of the 4 per-wave partials (barrier-sequenced)
    __shared__ float sred[4096];
    for (int wr = 0; wr < 4; wr++) {
        if (w == wr) {
            #pragma unroll
            for (int r = 0; r < 8; r++) {
                const int idx = (8 * si + r) * 64 + 8 * sj;
                if (wr == 0) {
                    *(float4*)&sred[idx]     = acc[r][0];
                    *(float4*)&sred[idx + 4] = acc[r][1];
                } else {
                    float4 v0 = *(float4*)&sred[idx];
                    float4 v1 = *(float4*)&sred[idx + 4];
                    v0.x += acc[r][0].x; v0.y += acc[r][0].y;
                    v0.z += acc[r][0].z; v0.w += acc[r][0].w;
                    v1.x += acc[r][1].x; v1.y += acc[r][1].y;
                    v1.z += acc[r][1].z; v1.w += acc[r][1].w;
                    *(float4*)&sred[idx]     = v0;
                    *(float4*)&sred[idx + 4] = v1;
                }
            }
        }
        __syncthreads();
    }

    float* pb = partial + (size_t)(b * nch + ch) * 4096;
    for (int i = 4 * tid; i < 4096; i += 1024)
        *(float4*)&pb[i] = *(const float4*)&sred[i];
}

// ---------------------------------------------------------------------------
// Kernel 2: reduce partials over chunks + softmax over d.
// Writes Mt[b, d, c] = softmax(S)[b, c, d] + (c==d)   (residual folded in).
// Block = (c, b), 64 threads = 1 wave, thread = d.
// ---------------------------------------------------------------------------
__global__ __launch_bounds__(64) void k2_softmax(const float* __restrict__ partial,
                                                 float* __restrict__ mt, int nch) {
    const int c = blockIdx.x;
    const int b = blockIdx.y;
    const int d = threadIdx.x;

    float s = 0.f;
    for (int ch = 0; ch < nch; ch++)
        s += partial[(size_t)(b * nch + ch) * 4096 + c * 64 + d];

    float m = s;
    #pragma unroll
    for (int off = 32; off > 0; off >>= 1) m = fmaxf(m, __shfl_xor(m, off));
    const float e = expf(s - m);
    float sum = e;
    #pragma unroll
    for (int off = 32; off > 0; off >>= 1) sum += __shfl_xor(sum, off);

    const float a = e / sum;
    mt[(size_t)b * 4096 + d * 64 + c] = a + (c == d ? 1.f : 0.f);
}

// ---------------------------------------------------------------------------
// Kernel 3: out[b,c,n] = sum_d Mt[b,d,c] * X[b, d*HW + n]
// Block = (n-chunk of 256, b), 256 threads = 4 waves (wave owns 64 n's).
// M (64x64) staged in LDS, broadcast reads; X streamed as float4.
// Lane (si,sj) computes an 8c x 8n register tile.
// ---------------------------------------------------------------------------
__global__ __launch_bounds__(256) void k3_out(const float* __restrict__ x,
                                              const float* __restrict__ mt,
                                              float* __restrict__ out) {
    const int nb   = blockIdx.x;
    const int b    = blockIdx.y;
    const int tid  = threadIdx.x;
    const int w    = tid >> 6;
    const int lane = tid & 63;
    const int si   = lane >> 3;   // c-octet
    const int sj   = lane & 7;    // n-octet within wave

    __shared__ float mlds[4096];
    {
        const float* mg = mt + (size_t)b * 4096;
        for (int i = 4 * tid; i < 4096; i += 1024)
            *(float4*)&mlds[i] = *(const float4*)&mg[i];
    }
    __syncthreads();

    const int n0 = nb * 256 + w * 64 + 8 * sj;
    const float* xp = x + (size_t)b * CHW_ + n0;

    float4 accA[8], accB[8];
    #pragma unroll
    for (int r = 0; r < 8; r++) {
        accA[r] = make_float4(0.f, 0.f, 0.f, 0.f);
        accB[r] = make_float4(0.f, 0.f, 0.f, 0.f);
    }

    #pragma unroll 4
    for (int d = 0; d < 64; d++) {
        const float4 xa = *(const float4*)(xp + (size_t)d * HW_);
        const float4 xb = *(const float4*)(xp + (size_t)d * HW_ + 4);
        const float4 ma = *(const float4*)&mlds[d * 64 + 8 * si];
        const float4 mb = *(const float4*)&mlds[d * 64 + 8 * si + 4];
        #pragma unroll
        for (int r = 0; r < 8; r++) {
            const float mv = (r < 4) ? comp4(ma, r) : comp4(mb, r - 4);
            accA[r].x += mv * xa.x;
            accA[r].y += mv * xa.y;
            accA[r].z += mv * xa.z;
            accA[r].w += mv * xa.w;
            accB[r].x += mv * xb.x;
            accB[r].y += mv * xb.y;
            accB[r].z += mv * xb.z;
            accB[r].w += mv * xb.w;
        }
    }

    float* op = out + (size_t)b * CHW_ + n0;
    #pragma unroll
    for (int r = 0; r < 8; r++) {
        *(float4*)(op + (size_t)(8 * si + r) * HW_)     = accA[r];
        *(float4*)(op + (size_t)(8 * si + r) * HW_ + 4) = accB[r];
    }
}

// ---------------------------------------------------------------------------
extern "C" void kernel_launch(void* const* d_in, const int* in_sizes, int n_in,
                              void* d_out, int out_size, void* d_ws, size_t ws_size,
                              hipStream_t stream) {
    const float* x = (const float*)d_in[0];
    float* out = (float*)d_out;

    float* wsf     = (float*)d_ws;
    float* mt      = wsf;                          // B*4096 floats = 256 KB
    float* partial = wsf + (size_t)B_ * 4096;      // B*nch*4096 floats

    // pick the largest chunk count whose partials fit in ws
    int nch = 64;
    while (nch > 1) {
        size_t need = (size_t)B_ * 4096 * sizeof(float)
                    + (size_t)B_ * nch * 4096 * sizeof(float);
        if (need <= ws_size) break;
        nch >>= 1;
    }
    const int nb = HW_ / nch;   // n's per k1 block

    k1_gram<<<dim3(nch, B_), 256, 0, stream>>>(x, partial, nch, nb);
    k2_softmax<<<dim3(C_, B_), 64, 0, stream>>>(partial, mt, nch);
    k3_out<<<dim3(HW_ / 256, B_), 256, 0, stream>>>(x, mt, out);
}

// Round 2
// 370.240 us; speedup vs baseline: 1.5538x; 1.5538x over previous
//
#include <hip/hip_runtime.h>

#define B_   16
#define C_   64
#define HW_  65536
#define CHW_ (C_ * HW_)   // 4194304 elements per batch
#define NT_  64           // n-tile per k1 step

__device__ __forceinline__ float comp4(float4 v, int i) {
    return i == 0 ? v.x : i == 1 ? v.y : i == 2 ? v.z : v.w;
}

// ---------------------------------------------------------------------------
// Kernel 1 v2: partial Gram.  S[b,c,d] = sum_n X[b,c*HW+n] * Xflat[b,n*64+d]
// Per 64-n step: stage Q transposed (QsT[n][c], pad 68) via column-gather
// (global reads 256B-contiguous/instr, LDS b128 writes conflict-minimal),
// stage K naturally (global reads 1KB-contiguous/instr).  4 waves split kk,
// each lane an 8x8 (c,d) register tile; cross-wave LDS reduce at the end.
// ---------------------------------------------------------------------------
__global__ __launch_bounds__(256, 4) void k1_gram(const float* __restrict__ x,
                                                  float* __restrict__ partial,
                                                  int nch, int nb) {
    const int ch   = blockIdx.x;
    const int b    = blockIdx.y;
    const int t    = threadIdx.x;
    const int w    = t >> 6;
    const int lane = t & 63;
    const int si   = lane >> 3;
    const int sj   = lane & 7;

    __shared__ float QsT[NT_][68];      // [n_local][c], pad 68 (16B-aligned rows)
    __shared__ float Ks[NT_ * C_];      // [n_local][d] natural, flat

    float4 acc[8][2];
    #pragma unroll
    for (int r = 0; r < 8; r++) {
        acc[r][0] = make_float4(0.f, 0.f, 0.f, 0.f);
        acc[r][1] = make_float4(0.f, 0.f, 0.f, 0.f);
    }

    const float* xb = x + (size_t)b * CHW_;
    const int nA = t & 63;     // staging n (same for Q gather)
    const int cq = t >> 6;     // wave id -> c-quad selector

    for (int nt = ch * nb; nt < ch * nb + nb; nt += NT_) {
        __syncthreads();   // protect tiles vs previous step's compute

        // --- stage Q transposed: thread gathers 4 consecutive c at one n ---
        #pragma unroll
        for (int p = 0; p < 4; p++) {
            const int c = 4 * (cq + 4 * p);          // 0,4,...,60 across passes
            const float* qp = xb + (size_t)c * HW_ + nt + nA;
            float4 v;
            v.x = qp[0];
            v.y = qp[(size_t)1 * HW_];
            v.z = qp[(size_t)2 * HW_];
            v.w = qp[(size_t)3 * HW_];
            *(float4*)&QsT[nA][c] = v;
        }
        // --- stage K: contiguous 16KB region, fully coalesced ---
        const float* kp = xb + (size_t)nt * C_;
        #pragma unroll
        for (int p = 0; p < 4; p++) {
            const int f = 4 * t + 1024 * p;
            *(float4*)&Ks[f] = *(const float4*)(kp + f);
        }
        __syncthreads();

        // --- compute: wave w owns kk in [16w, 16w+16) ---
        #pragma unroll
        for (int kk2 = 0; kk2 < 16; kk2++) {
            const int kk = 16 * w + kk2;
            const float4 q0  = *(const float4*)&QsT[kk][8 * si];
            const float4 q1  = *(const float4*)&QsT[kk][8 * si + 4];
            const float4 k0  = *(const float4*)&Ks[kk * C_ + 8 * sj];
            const float4 k1v = *(const float4*)&Ks[kk * C_ + 8 * sj + 4];
            #pragma unroll
            for (int r = 0; r < 8; r++) {
                const float qv = (r < 4) ? comp4(q0, r) : comp4(q1, r - 4);
                acc[r][0].x += qv * k0.x;
                acc[r][0].y += qv * k0.y;
                acc[r][0].z += qv * k0.z;
                acc[r][0].w += qv * k0.w;
                acc[r][1].x += qv * k1v.x;
                acc[r][1].y += qv * k1v.y;
                acc[r][1].z += qv * k1v.z;
                acc[r][1].w += qv * k1v.w;
            }
        }
    }

    __syncthreads();           // last compute done before aliasing Ks
    float* sred = Ks;          // reuse K tile as 64x64 reduction buffer
    for (int wr = 0; wr < 4; wr++) {
        if (w == wr) {
            #pragma unroll
            for (int r = 0; r < 8; r++) {
                const int idx = (8 * si + r) * 64 + 8 * sj;
                if (wr == 0) {
                    *(float4*)&sred[idx]     = acc[r][0];
                    *(float4*)&sred[idx + 4] = acc[r][1];
                } else {
                    float4 v0 = *(float4*)&sred[idx];
                    float4 v1 = *(float4*)&sred[idx + 4];
                    v0.x += acc[r][0].x; v0.y += acc[r][0].y;
                    v0.z += acc[r][0].z; v0.w += acc[r][0].w;
                    v1.x += acc[r][1].x; v1.y += acc[r][1].y;
                    v1.z += acc[r][1].z; v1.w += acc[r][1].w;
                    *(float4*)&sred[idx]     = v0;
                    *(float4*)&sred[idx + 4] = v1;
                }
            }
        }
        __syncthreads();
    }

    float* pb = partial + (size_t)(b * nch + ch) * 4096;
    for (int i = 4 * t; i < 4096; i += 1024)
        *(float4*)&pb[i] = *(const float4*)&sred[i];
}

// ---------------------------------------------------------------------------
// Kernel 2 v2: reduce partials + softmax.  256 threads per (c,b):
// waves split chunks, LDS reduce, wave 0 does the 64-wide softmax.
// Writes Mt[b,d,c] = softmax(S)[b,c,d] + (c==d)  (residual folded in).
// ---------------------------------------------------------------------------
__global__ __launch_bounds__(256) void k2_softmax(const float* __restrict__ partial,
                                                  float* __restrict__ mt, int nch) {
    const int c = blockIdx.x;
    const int b = blockIdx.y;
    const int t = threadIdx.x;
    const int w = t >> 6;
    const int d = t & 63;

    float s = 0.f;
    for (int ch = w; ch < nch; ch += 4)
        s += partial[(size_t)(b * nch + ch) * 4096 + c * 64 + d];

    __shared__ float red[256];
    red[t] = s;
    __syncthreads();
    if (w == 0) {
        s = red[d] + red[64 + d] + red[128 + d] + red[192 + d];
        float m = s;
        #pragma unroll
        for (int off = 32; off > 0; off >>= 1) m = fmaxf(m, __shfl_xor(m, off));
        const float e = expf(s - m);
        float sum = e;
        #pragma unroll
        for (int off = 32; off > 0; off >>= 1) sum += __shfl_xor(sum, off);
        mt[(size_t)b * 4096 + d * 64 + c] = e / sum + (c == d ? 1.f : 0.f);
    }
}

// ---------------------------------------------------------------------------
// Kernel 3 v2: out[b,c,n] = sum_d Mt[b,d,c] * X[b, d*HW + n]
// Block = 256 consecutive n; wave w owns c in [16w,16w+16); lane owns 4 n.
// x loads and out stores are 1KB-contiguous per wave instruction;
// M reads are LDS broadcasts (conflict-free).
// ---------------------------------------------------------------------------
__global__ __launch_bounds__(256, 4) void k3_out(const float* __restrict__ x,
                                                 const float* __restrict__ mt,
                                                 float* __restrict__ out) {
    const int nb   = blockIdx.x;
    const int b    = blockIdx.y;
    const int t    = threadIdx.x;
    const int w    = t >> 6;
    const int lane = t & 63;

    __shared__ float Ms[64 * 64];   // Mt[d][c]
    {
        const float* mg = mt + (size_t)b * 4096;
        for (int i = 4 * t; i < 4096; i += 1024)
            *(float4*)&Ms[i] = *(const float4*)&mg[i];
    }
    __syncthreads();

    const int c0 = 16 * w;
    const size_t nbase = (size_t)nb * 256 + 4 * lane;
    const float* xp = x + (size_t)b * CHW_ + nbase;

    float4 acc[16];
    #pragma unroll
    for (int r = 0; r < 16; r++) acc[r] = make_float4(0.f, 0.f, 0.f, 0.f);

    #pragma unroll 4
    for (int d = 0; d < 64; d++) {
        const float4 xv = *(const float4*)(xp + (size_t)d * HW_);
        const float4 m0 = *(const float4*)&Ms[d * 64 + c0];
        const float4 m1 = *(const float4*)&Ms[d * 64 + c0 + 4];
        const float4 m2 = *(const float4*)&Ms[d * 64 + c0 + 8];
        const float4 m3 = *(const float4*)&Ms[d * 64 + c0 + 12];
        #pragma unroll
        for (int r = 0; r < 4; r++) {
            const float mv = comp4(m0, r);
            acc[r].x += mv * xv.x; acc[r].y += mv * xv.y;
            acc[r].z += mv * xv.z; acc[r].w += mv * xv.w;
        }
        #pragma unroll
        for (int r = 0; r < 4; r++) {
            const float mv = comp4(m1, r);
            acc[4 + r].x += mv * xv.x; acc[4 + r].y += mv * xv.y;
            acc[4 + r].z += mv * xv.z; acc[4 + r].w += mv * xv.w;
        }
        #pragma unroll
        for (int r = 0; r < 4; r++) {
            const float mv = comp4(m2, r);
            acc[8 + r].x += mv * xv.x; acc[8 + r].y += mv * xv.y;
            acc[8 + r].z += mv * xv.z; acc[8 + r].w += mv * xv.w;
        }
        #pragma unroll
        for (int r = 0; r < 4; r++) {
            const float mv = comp4(m3, r);
            acc[12 + r].x += mv * xv.x; acc[12 + r].y += mv * xv.y;
            acc[12 + r].z += mv * xv.z; acc[12 + r].w += mv * xv.w;
        }
    }

    #pragma unroll
    for (int r = 0; r < 16; r++)
        *(float4*)(out + (size_t)b * CHW_ + (size_t)(c0 + r) * HW_ + nbase) = acc[r];
}

// ---------------------------------------------------------------------------
extern "C" void kernel_launch(void* const* d_in, const int* in_sizes, int n_in,
                              void* d_out, int out_size, void* d_ws, size_t ws_size,
                              hipStream_t stream) {
    const float* x = (const float*)d_in[0];
    float* out = (float*)d_out;

    float* wsf     = (float*)d_ws;
    float* mt      = wsf;                          // B*4096 floats
    float* partial = wsf + (size_t)B_ * 4096;      // B*nch*4096 floats

    int nch = 128;
    while (nch > 1) {
        size_t need = (size_t)B_ * 4096 * sizeof(float)
                    + (size_t)B_ * nch * 4096 * sizeof(float);
        if (need <= ws_size) break;
        nch >>= 1;
    }
    const int nb = HW_ / nch;

    k1_gram<<<dim3(nch, B_), 256, 0, stream>>>(x, partial, nch, nb);
    k2_softmax<<<dim3(C_, B_), 256, 0, stream>>>(partial, mt, nch);
    k3_out<<<dim3(HW_ / 256, B_), 256, 0, stream>>>(x, mt, out);
}